// Round 9
// baseline (1488.098 us; speedup 1.0000x reference)
//
#include <hip/hip_runtime.h>
#include <hip/hip_bf16.h>

#define D_DIM 512
#define H_DIM 512
#define O_DIM 768

using bf16x8 = __attribute__((ext_vector_type(8))) short;
using f32x4  = __attribute__((ext_vector_type(4))) float;

// packed fp32x2 -> bf16x2 (RNE), one VALU inst
static __device__ __forceinline__ unsigned cvtpk(float lo, float hi){
  unsigned r;
  asm("v_cvt_pk_bf16_f32 %0, %1, %2" : "=v"(r) : "v"(lo), "v"(hi));
  return r;
}

static __device__ __forceinline__ float bflo(unsigned u){
  return __uint_as_float(u << 16);
}
static __device__ __forceinline__ float bfhi(unsigned u){
  return __uint_as_float(u & 0xffff0000u);
}

static __device__ __forceinline__ float fast_tanh(float x){
  float e = __expf(2.f * x);         // inf-safe
  return 1.f - 2.f / (e + 1.f);
}

// ordered-uint encoding so atomicMax(unsigned) == float max
static __device__ __forceinline__ unsigned f2ord(float f){
  unsigned u = __float_as_uint(f);
  return (u & 0x80000000u) ? ~u : (u | 0x80000000u);
}
static __device__ __forceinline__ float ord2f(unsigned u){
  u = (u & 0x80000000u) ? (u & 0x7fffffffu) : ~u;
  return __uint_as_float(u);
}

// async global->LDS, 16B per lane, wave-uniform LDS base + lane*16 dest
static __device__ __forceinline__ void gload16(const void* g, void* l){
  __builtin_amdgcn_global_load_lds(
      (const __attribute__((address_space(1))) void*)g,
      (__attribute__((address_space(3))) void*)l, 16, 0, 0);
}

// ---------------------------------------------------------------------------
// fp32 -> bf16 pack (weights only; tiny)
// ---------------------------------------------------------------------------
__global__ void cvt_bf16(const float* __restrict__ in,
                         unsigned short* __restrict__ out, int n8)
{
  int stride = gridDim.x * blockDim.x;
  for (int i = blockIdx.x*blockDim.x + threadIdx.x; i < n8; i += stride){
    const float4* p = (const float4*)in + (size_t)i*2;
    float4 a = p[0], b = p[1];
    uint4 pk;
    pk.x = cvtpk(a.x, a.y);
    pk.y = cvtpk(a.z, a.w);
    pk.z = cvtpk(b.x, b.y);
    pk.w = cvtpk(b.z, b.w);
    ((uint4*)out)[i] = pk;
  }
}

// ---------------------------------------------------------------------------
// GEMM1 (high-occupancy): R4's serial staging order, BK=32 -> 16KB LDS ->
// ~6 blocks/CU (24 waves). Latency hidden by TLP, not in-block pipelining.
// Tile 128x128, 4 waves (2x2), per-wave 64x64, 16 K-steps.
// A: fp32 float4 reg-load -> cvt_pk -> swizzled ds_write (2-way-free reads:
// 16B granule g ^= (row>>1)&3). B: global_load_lds, source pre-swizzled.
// colBase==0 blocks emit packed bf16 A to Ab. Flat grid + bijective XCD
// chunked swizzle (N-fast, 4 col groups). Scores via atomicAdd partials.
// ---------------------------------------------------------------------------
__launch_bounds__(256, 6)
__global__ void gemm1_hc(const float* __restrict__ A,
                         const short* __restrict__ Bm,
                         const float* __restrict__ bias,
                         const float* __restrict__ w2,
                         float* __restrict__ out,
                         short* __restrict__ Ab,
                         int M, int nwg)
{
  __shared__ short lds_a[128*32];    // 8 KB
  __shared__ short lds_b[128*32];    // 8 KB

  // bijective XCD-chunked swizzle (m204), then N-fast decode
  const int q  = nwg >> 3, rr = nwg & 7;
  const int xcd = blockIdx.x & 7, bidx = blockIdx.x >> 3;
  const int swz = (xcd < rr ? xcd*(q+1) : rr*(q+1) + (xcd-rr)*q) + bidx;
  const int colBase = (swz & 3) * 128;
  const int rowBase = (swz >> 2) * 128;
  const bool writeAb = (colBase == 0);

  const int tid  = threadIdx.x;
  const int lane = tid & 63;
  const int w    = tid >> 6;
  const int wr   = w >> 1, wc = w & 1;
  const int lr   = lane & 15;
  const int lk   = lane >> 4;

  // A staging: 32 rows/pass (4 passes), 8 float4-granules per 128B fp32 row
  const int arow = tid >> 3;        // 0..31
  const int af4  = tid & 7;         // float4 granule (16B fp32 -> 8B bf16)
  // B staging: 16 rows/gload16-call, 4 16B-granules per 64B bf16 row
  const int rlocB = lane >> 2;      // 0..15
  const int jB    = lane & 3;

  f32x4 acc[4][4];
  #pragma unroll
  for (int i = 0; i < 4; ++i)
    #pragma unroll
    for (int j = 0; j < 4; ++j)
      acc[i][j] = (f32x4){0.f, 0.f, 0.f, 0.f};

  for (int kt = 0; kt < 16; ++kt){
    const int kOff = kt * 32;
    // A fp32 loads first (their drain leaves B gloads outstanding)
    float4 va[4];
    #pragma unroll
    for (int c = 0; c < 4; ++c){
      int gA = rowBase + c*32 + arow; if (gA > M-1) gA = M-1;
      va[c] = *(const float4*)(A + (size_t)gA*512 + kOff + af4*4);
    }
    // B async direct-to-LDS (2 calls/wave, source granule pre-swizzled)
    #pragma unroll
    for (int c = 0; c < 2; ++c){
      int rt = w*32 + c*16 + rlocB;
      int js = jB ^ ((rt >> 1) & 3);
      gload16(Bm + (size_t)(colBase + rt)*512 + kOff + js*8,
              &lds_b[(w*32 + c*16)*32]);
    }
    // cvt + swizzled ds_write A (+ packed bf16 A copy to global)
    #pragma unroll
    for (int c = 0; c < 4; ++c){
      int rt = c*32 + arow;
      uint2 pk = { cvtpk(va[c].x, va[c].y), cvtpk(va[c].z, va[c].w) };
      int g  = (af4 >> 1) ^ ((rt >> 1) & 3);          // 16B granule swizzle
      int si = rt*32 + g*8 + (af4 & 1)*4;             // short index
      *(uint2*)&lds_a[si] = pk;
      if (writeAb){
        int gA = rowBase + rt;
        if (gA < M) *(uint2*)(Ab + (size_t)gA*512 + kOff + af4*4) = pk;
      }
    }
    __syncthreads();   // drains vmcnt: lds_b ready; lds_a visible
    bf16x8 af[4], bfr[4];
    #pragma unroll
    for (int mf = 0; mf < 4; ++mf){
      int r  = wr*64 + mf*16 + lr;
      int g  = lk ^ ((r >> 1) & 3);
      af[mf] = *(bf16x8*)&lds_a[r*32 + g*8];
    }
    #pragma unroll
    for (int nf = 0; nf < 4; ++nf){
      int r  = wc*64 + nf*16 + lr;
      int g  = lk ^ ((r >> 1) & 3);
      bfr[nf] = *(bf16x8*)&lds_b[r*32 + g*8];
    }
    #pragma unroll
    for (int mf = 0; mf < 4; ++mf)
      #pragma unroll
      for (int nf = 0; nf < 4; ++nf)
        acc[mf][nf] = __builtin_amdgcn_mfma_f32_16x16x32_bf16(
            af[mf], bfr[nf], acc[mf][nf], 0, 0, 0);
    __syncthreads();
  }

  // scores epilogue: tanh + dot w2, reduce over 16 col-lanes, atomicAdd
  #pragma unroll
  for (int mf = 0; mf < 4; ++mf){
    float part[4] = {0.f,0.f,0.f,0.f};
    #pragma unroll
    for (int nf = 0; nf < 4; ++nf){
      int gc = colBase + wc*64 + nf*16 + lr;
      float b = bias[gc], wv = w2[gc];
      #pragma unroll
      for (int r = 0; r < 4; ++r)
        part[r] += fast_tanh(acc[mf][nf][r] + b) * wv;
    }
    #pragma unroll
    for (int r = 0; r < 4; ++r){
      part[r] += __shfl_xor(part[r], 1);
      part[r] += __shfl_xor(part[r], 2);
      part[r] += __shfl_xor(part[r], 4);
      part[r] += __shfl_xor(part[r], 8);
    }
    if (lr == 0){
      int gr = rowBase + wr*64 + mf*16 + lk*4;
      #pragma unroll
      for (int r = 0; r < 4; ++r)
        if (gr + r < M) atomicAdd(&out[gr + r], part[r]);
    }
  }
}

// ---------------------------------------------------------------------------
// GEMM2 + bias + LayerNorm fused: out = LN(aggb @ Wpb^T + bp) * gamma + beta
// Tile 64 rows x FULL 768 cols, 8 waves (1M x 8N), per-wave 64x96 = 4x6
// frags, BK=64. Full-row ownership -> in-block LN. Grid = P/64 = 256 blocks.
// ---------------------------------------------------------------------------
__launch_bounds__(512, 1)
__global__ void gemm2_ln(const short* __restrict__ A,
                         const short* __restrict__ Bm,
                         const float* __restrict__ bp,
                         const float* __restrict__ gamma,
                         const float* __restrict__ beta,
                         float* __restrict__ out)
{
  __shared__ short lds_a[64*64];      // 8 KB
  __shared__ short lds_b[768*64];     // 96 KB
  __shared__ float redS[64*8];
  __shared__ float redQ[64*8];
  __shared__ float muArr[64];
  __shared__ float invArr[64];

  const int tid  = threadIdx.x;
  const int lane = tid & 63;
  const int w    = tid >> 6;          // 0..7 (N)
  const int lr   = lane & 15;
  const int lk   = lane >> 4;
  const int rowBase = blockIdx.x * 64;
  const int rloc = lane >> 3;
  const int jg   = lane & 7;

  f32x4 acc[4][6];
  #pragma unroll
  for (int i = 0; i < 4; ++i)
    #pragma unroll
    for (int j = 0; j < 6; ++j)
      acc[i][j] = (f32x4){0.f, 0.f, 0.f, 0.f};

  for (int kt = 0; kt < 8; ++kt){
    const int kOff = kt * 64;
    {
      int rt = w*8 + rloc;
      int js = jg ^ (rt & 7);
      gload16(A + (size_t)(rowBase + rt)*512 + kOff + js*8, &lds_a[(w*8)*64]);
    }
    #pragma unroll
    for (int c = 0; c < 12; ++c){
      int rt = w*96 + c*8 + rloc;
      int js = jg ^ (rt & 7);
      gload16(Bm + (size_t)rt*512 + kOff + js*8, &lds_b[(w*96 + c*8)*64]);
    }
    __syncthreads();
    #pragma unroll
    for (int kk = 0; kk < 2; ++kk){
      bf16x8 af[4], bfr[6];
      #pragma unroll
      for (int mf = 0; mf < 4; ++mf){
        int r   = mf*16 + lr;
        int idx = (r*64 + kk*32 + lk*8) ^ ((r & 7) << 3);
        af[mf] = *(bf16x8*)&lds_a[idx];
      }
      #pragma unroll
      for (int nf = 0; nf < 6; ++nf){
        int r   = w*96 + nf*16 + lr;
        int idx = (r*64 + kk*32 + lk*8) ^ ((r & 7) << 3);
        bfr[nf] = *(bf16x8*)&lds_b[idx];
      }
      __builtin_amdgcn_s_setprio(1);
      #pragma unroll
      for (int mf = 0; mf < 4; ++mf)
        #pragma unroll
        for (int nf = 0; nf < 6; ++nf)
          acc[mf][nf] = __builtin_amdgcn_mfma_f32_16x16x32_bf16(
              af[mf], bfr[nf], acc[mf][nf], 0, 0, 0);
      __builtin_amdgcn_s_setprio(0);
    }
    __syncthreads();
  }

  // per-row stats over this wave's 96 cols (bias included)
  float s1[4][4], s2[4][4];
  #pragma unroll
  for (int mf = 0; mf < 4; ++mf)
    #pragma unroll
    for (int r = 0; r < 4; ++r){ s1[mf][r] = 0.f; s2[mf][r] = 0.f; }
  #pragma unroll
  for (int mf = 0; mf < 4; ++mf)
    #pragma unroll
    for (int nf = 0; nf < 6; ++nf){
      int gc = w*96 + nf*16 + lr;
      float b = bp[gc];
      #pragma unroll
      for (int r = 0; r < 4; ++r){
        float v = acc[mf][nf][r] + b;
        s1[mf][r] += v;
        s2[mf][r] += v*v;
      }
    }
  #pragma unroll
  for (int mf = 0; mf < 4; ++mf)
    #pragma unroll
    for (int r = 0; r < 4; ++r){
      #pragma unroll
      for (int d = 1; d < 16; d <<= 1){
        s1[mf][r] += __shfl_xor(s1[mf][r], d);
        s2[mf][r] += __shfl_xor(s2[mf][r], d);
      }
    }
  if (lr == 0){
    #pragma unroll
    for (int mf = 0; mf < 4; ++mf)
      #pragma unroll
      for (int r = 0; r < 4; ++r){
        int row = mf*16 + lk*4 + r;
        redS[row*8 + w] = s1[mf][r];
        redQ[row*8 + w] = s2[mf][r];
      }
  }
  __syncthreads();
  if (tid < 64){
    float s = 0.f, qq = 0.f;
    #pragma unroll
    for (int j = 0; j < 8; ++j){ s += redS[tid*8 + j]; qq += redQ[tid*8 + j]; }
    float mu  = s * (1.f/768.f);
    float var = qq * (1.f/768.f) - mu*mu;
    muArr[tid]  = mu;
    invArr[tid] = rsqrtf(var + 1e-5f);
  }
  __syncthreads();

  #pragma unroll
  for (int mf = 0; mf < 4; ++mf)
    #pragma unroll
    for (int nf = 0; nf < 6; ++nf){
      int gc = w*96 + nf*16 + lr;
      float b = bp[gc], g = gamma[gc], be = beta[gc];
      #pragma unroll
      for (int r = 0; r < 4; ++r){
        int row = mf*16 + lk*4 + r;
        float v = acc[mf][nf][r] + b;
        out[(size_t)(rowBase + row)*768 + gc] =
            (v - muArr[row]) * invArr[row] * g + be;
      }
    }
}

// ---------------------------------------------------------------------------
__global__ void edge_pass1(const int* __restrict__ edge, int E,
                           const float* __restrict__ scores,
                           unsigned* __restrict__ smax_o,
                           int* __restrict__ hist)
{
  int e = blockIdx.x*256 + threadIdx.x;
  if (e >= E) return;
  int p = edge[e], l = edge[E + e];
  atomicMax(&smax_o[p], f2ord(scores[l]));
  atomicAdd(&hist[p], 1);
}

__global__ void scan_kernel(const int* __restrict__ hist,
                            int* __restrict__ offsets, int P)
{
  __shared__ int s[1024];
  int t = threadIdx.x;
  int local[16]; int sum = 0;
  #pragma unroll
  for (int i = 0; i < 16; ++i){
    int idx = t*16 + i;
    local[i] = (idx < P) ? hist[idx] : 0;
    sum += local[i];
  }
  s[t] = sum;
  __syncthreads();
  for (int off = 1; off < 1024; off <<= 1){
    int v = (t >= off) ? s[t - off] : 0;
    __syncthreads();
    s[t] += v;
    __syncthreads();
  }
  int run = s[t] - sum;             // exclusive prefix
  #pragma unroll
  for (int i = 0; i < 16; ++i){
    int idx = t*16 + i;
    if (idx < P) offsets[idx] = run;
    run += local[i];
  }
}

__global__ void edge_pass2(const int* __restrict__ edge, int E,
                           const float* __restrict__ scores,
                           const unsigned* __restrict__ smax_o,
                           float* __restrict__ ex,
                           float* __restrict__ esum,
                           const int* __restrict__ offsets,
                           int* __restrict__ cursor,
                           int* __restrict__ sorted)
{
  int e = blockIdx.x*256 + threadIdx.x;
  if (e >= E) return;
  int p = edge[e], l = edge[E + e];
  float v = __expf(scores[l] - ord2f(smax_o[p]));
  ex[e] = v;
  atomicAdd(&esum[p], v);
  int pos = atomicAdd(&cursor[p], 1);
  sorted[offsets[p] + pos] = e;
}

// one WAVE per patient (4/block), bf16 gather with 1-ahead prefetch
__global__ void agg_kernel(const int* __restrict__ edge, int E,
                           const short* __restrict__ Ab,
                           const float* __restrict__ ex,
                           const float* __restrict__ esum,
                           const int* __restrict__ offsets,
                           const int* __restrict__ hist,
                           const int* __restrict__ sorted,
                           unsigned* __restrict__ aggb)
{
  int p    = blockIdx.x*4 + (threadIdx.x >> 6);
  int lane = threadIdx.x & 63;
  int n = hist[p];
  if (n == 0) return;               // row stays zero (memset)
  int start = offsets[p];
  float inv = 1.f / fmaxf(esum[p], 1e-12f);
  float a[8] = {0.f,0.f,0.f,0.f,0.f,0.f,0.f,0.f};
  int e0 = sorted[start];
  uint4 u = *(const uint4*)(Ab + (size_t)edge[E + e0]*512 + lane*8);
  float alpha = ex[e0] * inv;
  for (int i = 0; i < n; ++i){
    uint4 uc = u; float ac = alpha;
    if (i + 1 < n){
      int e2 = sorted[start + i + 1];
      u = *(const uint4*)(Ab + (size_t)edge[E + e2]*512 + lane*8);
      alpha = ex[e2] * inv;
    }
    a[0] += ac * bflo(uc.x);  a[1] += ac * bfhi(uc.x);
    a[2] += ac * bflo(uc.y);  a[3] += ac * bfhi(uc.y);
    a[4] += ac * bflo(uc.z);  a[5] += ac * bfhi(uc.z);
    a[6] += ac * bflo(uc.w);  a[7] += ac * bfhi(uc.w);
  }
  uint4 o = { cvtpk(a[0],a[1]), cvtpk(a[2],a[3]),
              cvtpk(a[4],a[5]), cvtpk(a[6],a[7]) };
  *(uint4*)&aggb[(size_t)p*256 + lane*4] = o;
}

// ---------------------------------------------------------------------------
extern "C" void kernel_launch(void* const* d_in, const int* in_sizes, int n_in,
                              void* d_out, int out_size, void* d_ws, size_t ws_size,
                              hipStream_t stream)
{
  const float* lesion_x = (const float*)d_in[0];
  const int*   edge     = (const int*)d_in[1];
  const float* W1    = (const float*)d_in[3];
  const float* b1    = (const float*)d_in[4];
  const float* W2    = (const float*)d_in[5];
  // d_in[6] = b2 — uniform shift, cancels in softmax
  const float* Wp    = (const float*)d_in[7];
  const float* bp    = (const float*)d_in[8];
  const float* gamma = (const float*)d_in[9];
  const float* beta  = (const float*)d_in[10];

  const int L = in_sizes[0] / D_DIM;
  const int E = in_sizes[1] / 2;
  const int P = out_size / O_DIM;

  auto al = [](size_t x){ return (x + 255) & ~(size_t)255; };
  char* ws = (char*)d_ws;
  size_t oScores = 0;
  size_t oSmax   = oScores + al((size_t)L*4);
  size_t oEsum   = oSmax   + al((size_t)P*4);
  size_t oHist   = oEsum   + al((size_t)P*4);
  size_t oCursor = oHist   + al((size_t)P*4);
  size_t smallEnd= oCursor + al((size_t)P*4);
  size_t oAggB   = smallEnd;                        // P*512*2 bf16
  size_t aggEnd  = oAggB   + al((size_t)P*D_DIM*2);
  size_t oOff    = aggEnd;
  size_t oEx     = oOff    + al((size_t)P*4);
  size_t oSorted = oEx     + al((size_t)E*4);
  size_t oW1b    = oSorted + al((size_t)E*4);
  size_t oWpb    = oW1b    + al((size_t)H_DIM*D_DIM*2);
  size_t oAb     = oWpb    + al((size_t)O_DIM*D_DIM*2);
  size_t need    = oAb     + al((size_t)L*D_DIM*2);
  (void)need; // ~230 MB; harness ws is ~1.6 GB

  float*    scores = (float*)(ws + oScores);
  unsigned* smax_o = (unsigned*)(ws + oSmax);
  float*    esum   = (float*)(ws + oEsum);
  int*      hist   = (int*)(ws + oHist);
  int*      cursor = (int*)(ws + oCursor);
  unsigned* aggb   = (unsigned*)(ws + oAggB);
  int*      offs   = (int*)(ws + oOff);
  float*    ex     = (float*)(ws + oEx);
  int*      sorted = (int*)(ws + oSorted);
  short*    W1b    = (short*)(ws + oW1b);
  short*    Wpb    = (short*)(ws + oWpb);
  short*    Ab     = (short*)(ws + oAb);

  hipMemsetAsync(d_ws, 0, smallEnd, stream);
  hipMemsetAsync(ws + oAggB, 0, (size_t)P*D_DIM*2, stream);

  dim3 b256(256);
  int eb = (E + 255) / 256;

  // weight conversions (tiny, BW-bound)
  cvt_bf16<<<128, b256, 0, stream>>>(W1, (unsigned short*)W1b, H_DIM*D_DIM/8);
  cvt_bf16<<<192, b256, 0, stream>>>(Wp, (unsigned short*)Wpb, O_DIM*D_DIM/8);

  // GEMM1: BK=32 high-occupancy; fp32 A reg-staged -> bf16 LDS; emits Ab
  int nRow = (L + 127) / 128;
  int nwg  = 4 * nRow;
  gemm1_hc<<<nwg, b256, 0, stream>>>(lesion_x, W1b, b1, W2, scores, Ab, L, nwg);

  edge_pass1<<<eb, b256, 0, stream>>>(edge, E, scores, smax_o, hist);
  scan_kernel<<<1, 1024, 0, stream>>>(hist, offs, P);
  edge_pass2<<<eb, b256, 0, stream>>>(edge, E, scores, smax_o, ex, esum,
                                      offs, cursor, sorted);
  agg_kernel<<<P/4, b256, 0, stream>>>(edge, E, Ab, ex, esum, offs,
                                       hist, sorted, aggb);
  // GEMM2 + bias + LayerNorm fused (full 768-col rows per block)
  gemm2_ln<<<P/64, dim3(512), 0, stream>>>((const short*)aggb, Wpb, bp,
                                           gamma, beta, (float*)d_out);
}

// Round 10
// 428.584 us; speedup vs baseline: 3.4721x; 3.4721x over previous
//
#include <hip/hip_runtime.h>
#include <hip/hip_bf16.h>

#define D_DIM 512
#define H_DIM 512
#define O_DIM 768

using bf16x8 = __attribute__((ext_vector_type(8))) short;
using f32x4  = __attribute__((ext_vector_type(4))) float;

// packed fp32x2 -> bf16x2 (RNE), one VALU inst
static __device__ __forceinline__ unsigned cvtpk(float lo, float hi){
  unsigned r;
  asm("v_cvt_pk_bf16_f32 %0, %1, %2" : "=v"(r) : "v"(lo), "v"(hi));
  return r;
}

static __device__ __forceinline__ float bflo(unsigned u){
  return __uint_as_float(u << 16);
}
static __device__ __forceinline__ float bfhi(unsigned u){
  return __uint_as_float(u & 0xffff0000u);
}

static __device__ __forceinline__ float fast_tanh(float x){
  float e = __expf(2.f * x);         // inf-safe
  return 1.f - 2.f / (e + 1.f);
}

// ordered-uint encoding so atomicMax(unsigned) == float max
static __device__ __forceinline__ unsigned f2ord(float f){
  unsigned u = __float_as_uint(f);
  return (u & 0x80000000u) ? ~u : (u | 0x80000000u);
}
static __device__ __forceinline__ float ord2f(unsigned u){
  u = (u & 0x80000000u) ? (u & 0x7fffffffu) : ~u;
  return __uint_as_float(u);
}

// async global->LDS, 16B per lane, wave-uniform LDS base + lane*16 dest
static __device__ __forceinline__ void gload16(const void* g, void* l){
  __builtin_amdgcn_global_load_lds(
      (const __attribute__((address_space(1))) void*)g,
      (__attribute__((address_space(3))) void*)l, 16, 0, 0);
}

// ---------------------------------------------------------------------------
// fp32 -> bf16 pack (weights only; tiny)
// ---------------------------------------------------------------------------
__global__ void cvt_bf16(const float* __restrict__ in,
                         unsigned short* __restrict__ out, int n8)
{
  int stride = gridDim.x * blockDim.x;
  for (int i = blockIdx.x*blockDim.x + threadIdx.x; i < n8; i += stride){
    const float4* p = (const float4*)in + (size_t)i*2;
    float4 a = p[0], b = p[1];
    uint4 pk;
    pk.x = cvtpk(a.x, a.y);
    pk.y = cvtpk(a.z, a.w);
    pk.z = cvtpk(b.x, b.y);
    pk.w = cvtpk(b.z, b.w);
    ((uint4*)out)[i] = pk;
  }
}

// ---------------------------------------------------------------------------
// GEMM1 (high-occupancy, spill-fixed): BK=32 -> 16KB LDS; launch_bounds
// (256,4) -> VGPR cap 128 (R9's (256,6) capped at 85 and spilled acc ->
// 5.5GB scratch traffic). Tile 128x128, 4 waves (2x2), 16 K-steps.
// A: fp32 float4 reg-load -> cvt_pk -> swizzled ds_write (2-way-free reads).
// B: global_load_lds, source pre-swizzled. colBase==0 blocks emit bf16 Ab.
// Flat grid + bijective XCD chunked swizzle (N-fast). Scores via atomicAdd.
// ---------------------------------------------------------------------------
__launch_bounds__(256, 4)
__global__ void gemm1_hc(const float* __restrict__ A,
                         const short* __restrict__ Bm,
                         const float* __restrict__ bias,
                         const float* __restrict__ w2,
                         float* __restrict__ out,
                         short* __restrict__ Ab,
                         int M, int nwg)
{
  __shared__ short lds_a[128*32];    // 8 KB
  __shared__ short lds_b[128*32];    // 8 KB

  // bijective XCD-chunked swizzle (m204), then N-fast decode
  const int q  = nwg >> 3, rr = nwg & 7;
  const int xcd = blockIdx.x & 7, bidx = blockIdx.x >> 3;
  const int swz = (xcd < rr ? xcd*(q+1) : rr*(q+1) + (xcd-rr)*q) + bidx;
  const int colBase = (swz & 3) * 128;
  const int rowBase = (swz >> 2) * 128;
  const bool writeAb = (colBase == 0);

  const int tid  = threadIdx.x;
  const int lane = tid & 63;
  const int w    = tid >> 6;
  const int wr   = w >> 1, wc = w & 1;
  const int lr   = lane & 15;
  const int lk   = lane >> 4;

  // A staging: 32 rows/pass (4 passes), 8 float4-granules per 128B fp32 row
  const int arow = tid >> 3;        // 0..31
  const int af4  = tid & 7;         // float4 granule (16B fp32 -> 8B bf16)
  // B staging: 16 rows/gload16-call, 4 16B-granules per 64B bf16 row
  const int rlocB = lane >> 2;      // 0..15
  const int jB    = lane & 3;

  f32x4 acc[4][4];
  #pragma unroll
  for (int i = 0; i < 4; ++i)
    #pragma unroll
    for (int j = 0; j < 4; ++j)
      acc[i][j] = (f32x4){0.f, 0.f, 0.f, 0.f};

  for (int kt = 0; kt < 16; ++kt){
    const int kOff = kt * 32;
    // A fp32 loads first (their drain leaves B gloads outstanding)
    float4 va[4];
    #pragma unroll
    for (int c = 0; c < 4; ++c){
      int gA = rowBase + c*32 + arow; if (gA > M-1) gA = M-1;
      va[c] = *(const float4*)(A + (size_t)gA*512 + kOff + af4*4);
    }
    // B async direct-to-LDS (2 calls/wave, source granule pre-swizzled)
    #pragma unroll
    for (int c = 0; c < 2; ++c){
      int rt = w*32 + c*16 + rlocB;
      int js = jB ^ ((rt >> 1) & 3);
      gload16(Bm + (size_t)(colBase + rt)*512 + kOff + js*8,
              &lds_b[(w*32 + c*16)*32]);
    }
    // cvt + swizzled ds_write A (+ packed bf16 A copy to global)
    #pragma unroll
    for (int c = 0; c < 4; ++c){
      int rt = c*32 + arow;
      uint2 pk = { cvtpk(va[c].x, va[c].y), cvtpk(va[c].z, va[c].w) };
      int g  = (af4 >> 1) ^ ((rt >> 1) & 3);          // 16B granule swizzle
      int si = rt*32 + g*8 + (af4 & 1)*4;             // short index
      *(uint2*)&lds_a[si] = pk;
      if (writeAb){
        int gA = rowBase + rt;
        if (gA < M) *(uint2*)(Ab + (size_t)gA*512 + kOff + af4*4) = pk;
      }
    }
    __syncthreads();   // drains vmcnt: lds_b ready; lds_a visible
    bf16x8 af[4], bfr[4];
    #pragma unroll
    for (int mf = 0; mf < 4; ++mf){
      int r  = wr*64 + mf*16 + lr;
      int g  = lk ^ ((r >> 1) & 3);
      af[mf] = *(bf16x8*)&lds_a[r*32 + g*8];
    }
    #pragma unroll
    for (int nf = 0; nf < 4; ++nf){
      int r  = wc*64 + nf*16 + lr;
      int g  = lk ^ ((r >> 1) & 3);
      bfr[nf] = *(bf16x8*)&lds_b[r*32 + g*8];
    }
    #pragma unroll
    for (int mf = 0; mf < 4; ++mf)
      #pragma unroll
      for (int nf = 0; nf < 4; ++nf)
        acc[mf][nf] = __builtin_amdgcn_mfma_f32_16x16x32_bf16(
            af[mf], bfr[nf], acc[mf][nf], 0, 0, 0);
    __syncthreads();
  }

  // scores epilogue: tanh + dot w2, reduce over 16 col-lanes, atomicAdd
  #pragma unroll
  for (int mf = 0; mf < 4; ++mf){
    float part[4] = {0.f,0.f,0.f,0.f};
    #pragma unroll
    for (int nf = 0; nf < 4; ++nf){
      int gc = colBase + wc*64 + nf*16 + lr;
      float b = bias[gc], wv = w2[gc];
      #pragma unroll
      for (int r = 0; r < 4; ++r)
        part[r] += fast_tanh(acc[mf][nf][r] + b) * wv;
    }
    #pragma unroll
    for (int r = 0; r < 4; ++r){
      part[r] += __shfl_xor(part[r], 1);
      part[r] += __shfl_xor(part[r], 2);
      part[r] += __shfl_xor(part[r], 4);
      part[r] += __shfl_xor(part[r], 8);
    }
    if (lr == 0){
      int gr = rowBase + wr*64 + mf*16 + lk*4;
      #pragma unroll
      for (int r = 0; r < 4; ++r)
        if (gr + r < M) atomicAdd(&out[gr + r], part[r]);
    }
  }
}

// ---------------------------------------------------------------------------
// GEMM2 + bias + LayerNorm fused: out = LN(aggb @ Wpb^T + bp) * gamma + beta
// Tile 64 rows x FULL 768 cols, 8 waves (1M x 8N), per-wave 64x96 = 4x6
// frags, BK=64. Full-row ownership -> in-block LN. Grid = P/64 = 256 blocks.
// ---------------------------------------------------------------------------
__launch_bounds__(512, 1)
__global__ void gemm2_ln(const short* __restrict__ A,
                         const short* __restrict__ Bm,
                         const float* __restrict__ bp,
                         const float* __restrict__ gamma,
                         const float* __restrict__ beta,
                         float* __restrict__ out)
{
  __shared__ short lds_a[64*64];      // 8 KB
  __shared__ short lds_b[768*64];     // 96 KB
  __shared__ float redS[64*8];
  __shared__ float redQ[64*8];
  __shared__ float muArr[64];
  __shared__ float invArr[64];

  const int tid  = threadIdx.x;
  const int lane = tid & 63;
  const int w    = tid >> 6;          // 0..7 (N)
  const int lr   = lane & 15;
  const int lk   = lane >> 4;
  const int rowBase = blockIdx.x * 64;
  const int rloc = lane >> 3;
  const int jg   = lane & 7;

  f32x4 acc[4][6];
  #pragma unroll
  for (int i = 0; i < 4; ++i)
    #pragma unroll
    for (int j = 0; j < 6; ++j)
      acc[i][j] = (f32x4){0.f, 0.f, 0.f, 0.f};

  for (int kt = 0; kt < 8; ++kt){
    const int kOff = kt * 64;
    {
      int rt = w*8 + rloc;
      int js = jg ^ (rt & 7);
      gload16(A + (size_t)(rowBase + rt)*512 + kOff + js*8, &lds_a[(w*8)*64]);
    }
    #pragma unroll
    for (int c = 0; c < 12; ++c){
      int rt = w*96 + c*8 + rloc;
      int js = jg ^ (rt & 7);
      gload16(Bm + (size_t)rt*512 + kOff + js*8, &lds_b[(w*96 + c*8)*64]);
    }
    __syncthreads();
    #pragma unroll
    for (int kk = 0; kk < 2; ++kk){
      bf16x8 af[4], bfr[6];
      #pragma unroll
      for (int mf = 0; mf < 4; ++mf){
        int r   = mf*16 + lr;
        int idx = (r*64 + kk*32 + lk*8) ^ ((r & 7) << 3);
        af[mf] = *(bf16x8*)&lds_a[idx];
      }
      #pragma unroll
      for (int nf = 0; nf < 6; ++nf){
        int r   = w*96 + nf*16 + lr;
        int idx = (r*64 + kk*32 + lk*8) ^ ((r & 7) << 3);
        bfr[nf] = *(bf16x8*)&lds_b[idx];
      }
      __builtin_amdgcn_s_setprio(1);
      #pragma unroll
      for (int mf = 0; mf < 4; ++mf)
        #pragma unroll
        for (int nf = 0; nf < 6; ++nf)
          acc[mf][nf] = __builtin_amdgcn_mfma_f32_16x16x32_bf16(
              af[mf], bfr[nf], acc[mf][nf], 0, 0, 0);
      __builtin_amdgcn_s_setprio(0);
    }
    __syncthreads();
  }

  // per-row stats over this wave's 96 cols (bias included)
  float s1[4][4], s2[4][4];
  #pragma unroll
  for (int mf = 0; mf < 4; ++mf)
    #pragma unroll
    for (int r = 0; r < 4; ++r){ s1[mf][r] = 0.f; s2[mf][r] = 0.f; }
  #pragma unroll
  for (int mf = 0; mf < 4; ++mf)
    #pragma unroll
    for (int nf = 0; nf < 6; ++nf){
      int gc = w*96 + nf*16 + lr;
      float b = bp[gc];
      #pragma unroll
      for (int r = 0; r < 4; ++r){
        float v = acc[mf][nf][r] + b;
        s1[mf][r] += v;
        s2[mf][r] += v*v;
      }
    }
  #pragma unroll
  for (int mf = 0; mf < 4; ++mf)
    #pragma unroll
    for (int r = 0; r < 4; ++r){
      #pragma unroll
      for (int d = 1; d < 16; d <<= 1){
        s1[mf][r] += __shfl_xor(s1[mf][r], d);
        s2[mf][r] += __shfl_xor(s2[mf][r], d);
      }
    }
  if (lr == 0){
    #pragma unroll
    for (int mf = 0; mf < 4; ++mf)
      #pragma unroll
      for (int r = 0; r < 4; ++r){
        int row = mf*16 + lk*4 + r;
        redS[row*8 + w] = s1[mf][r];
        redQ[row*8 + w] = s2[mf][r];
      }
  }
  __syncthreads();
  if (tid < 64){
    float s = 0.f, qq = 0.f;
    #pragma unroll
    for (int j = 0; j < 8; ++j){ s += redS[tid*8 + j]; qq += redQ[tid*8 + j]; }
    float mu  = s * (1.f/768.f);
    float var = qq * (1.f/768.f) - mu*mu;
    muArr[tid]  = mu;
    invArr[tid] = rsqrtf(var + 1e-5f);
  }
  __syncthreads();

  #pragma unroll
  for (int mf = 0; mf < 4; ++mf)
    #pragma unroll
    for (int nf = 0; nf < 6; ++nf){
      int gc = w*96 + nf*16 + lr;
      float b = bp[gc], g = gamma[gc], be = beta[gc];
      #pragma unroll
      for (int r = 0; r < 4; ++r){
        int row = mf*16 + lk*4 + r;
        float v = acc[mf][nf][r] + b;
        out[(size_t)(rowBase + row)*768 + gc] =
            (v - muArr[row]) * invArr[row] * g + be;
      }
    }
}

// ---------------------------------------------------------------------------
__global__ void edge_pass1(const int* __restrict__ edge, int E,
                           const float* __restrict__ scores,
                           unsigned* __restrict__ smax_o,
                           int* __restrict__ hist)
{
  int e = blockIdx.x*256 + threadIdx.x;
  if (e >= E) return;
  int p = edge[e], l = edge[E + e];
  atomicMax(&smax_o[p], f2ord(scores[l]));
  atomicAdd(&hist[p], 1);
}

__global__ void scan_kernel(const int* __restrict__ hist,
                            int* __restrict__ offsets, int P)
{
  __shared__ int s[1024];
  int t = threadIdx.x;
  int local[16]; int sum = 0;
  #pragma unroll
  for (int i = 0; i < 16; ++i){
    int idx = t*16 + i;
    local[i] = (idx < P) ? hist[idx] : 0;
    sum += local[i];
  }
  s[t] = sum;
  __syncthreads();
  for (int off = 1; off < 1024; off <<= 1){
    int v = (t >= off) ? s[t - off] : 0;
    __syncthreads();
    s[t] += v;
    __syncthreads();
  }
  int run = s[t] - sum;             // exclusive prefix
  #pragma unroll
  for (int i = 0; i < 16; ++i){
    int idx = t*16 + i;
    if (idx < P) offsets[idx] = run;
    run += local[i];
  }
}

__global__ void edge_pass2(const int* __restrict__ edge, int E,
                           const float* __restrict__ scores,
                           const unsigned* __restrict__ smax_o,
                           float* __restrict__ ex,
                           float* __restrict__ esum,
                           const int* __restrict__ offsets,
                           int* __restrict__ cursor,
                           int* __restrict__ sorted)
{
  int e = blockIdx.x*256 + threadIdx.x;
  if (e >= E) return;
  int p = edge[e], l = edge[E + e];
  float v = __expf(scores[l] - ord2f(smax_o[p]));
  ex[e] = v;
  atomicAdd(&esum[p], v);
  int pos = atomicAdd(&cursor[p], 1);
  sorted[offsets[p] + pos] = e;
}

// one WAVE per patient (4/block), bf16 gather with 1-ahead prefetch
__global__ void agg_kernel(const int* __restrict__ edge, int E,
                           const short* __restrict__ Ab,
                           const float* __restrict__ ex,
                           const float* __restrict__ esum,
                           const int* __restrict__ offsets,
                           const int* __restrict__ hist,
                           const int* __restrict__ sorted,
                           unsigned* __restrict__ aggb)
{
  int p    = blockIdx.x*4 + (threadIdx.x >> 6);
  int lane = threadIdx.x & 63;
  int n = hist[p];
  if (n == 0) return;               // row stays zero (memset)
  int start = offsets[p];
  float inv = 1.f / fmaxf(esum[p], 1e-12f);
  float a[8] = {0.f,0.f,0.f,0.f,0.f,0.f,0.f,0.f};
  int e0 = sorted[start];
  uint4 u = *(const uint4*)(Ab + (size_t)edge[E + e0]*512 + lane*8);
  float alpha = ex[e0] * inv;
  for (int i = 0; i < n; ++i){
    uint4 uc = u; float ac = alpha;
    if (i + 1 < n){
      int e2 = sorted[start + i + 1];
      u = *(const uint4*)(Ab + (size_t)edge[E + e2]*512 + lane*8);
      alpha = ex[e2] * inv;
    }
    a[0] += ac * bflo(uc.x);  a[1] += ac * bfhi(uc.x);
    a[2] += ac * bflo(uc.y);  a[3] += ac * bfhi(uc.y);
    a[4] += ac * bflo(uc.z);  a[5] += ac * bfhi(uc.z);
    a[6] += ac * bflo(uc.w);  a[7] += ac * bfhi(uc.w);
  }
  uint4 o = { cvtpk(a[0],a[1]), cvtpk(a[2],a[3]),
              cvtpk(a[4],a[5]), cvtpk(a[6],a[7]) };
  *(uint4*)&aggb[(size_t)p*256 + lane*4] = o;
}

// ---------------------------------------------------------------------------
extern "C" void kernel_launch(void* const* d_in, const int* in_sizes, int n_in,
                              void* d_out, int out_size, void* d_ws, size_t ws_size,
                              hipStream_t stream)
{
  const float* lesion_x = (const float*)d_in[0];
  const int*   edge     = (const int*)d_in[1];
  const float* W1    = (const float*)d_in[3];
  const float* b1    = (const float*)d_in[4];
  const float* W2    = (const float*)d_in[5];
  // d_in[6] = b2 — uniform shift, cancels in softmax
  const float* Wp    = (const float*)d_in[7];
  const float* bp    = (const float*)d_in[8];
  const float* gamma = (const float*)d_in[9];
  const float* beta  = (const float*)d_in[10];

  const int L = in_sizes[0] / D_DIM;
  const int E = in_sizes[1] / 2;
  const int P = out_size / O_DIM;

  auto al = [](size_t x){ return (x + 255) & ~(size_t)255; };
  char* ws = (char*)d_ws;
  size_t oScores = 0;
  size_t oSmax   = oScores + al((size_t)L*4);
  size_t oEsum   = oSmax   + al((size_t)P*4);
  size_t oHist   = oEsum   + al((size_t)P*4);
  size_t oCursor = oHist   + al((size_t)P*4);
  size_t smallEnd= oCursor + al((size_t)P*4);
  size_t oAggB   = smallEnd;                        // P*512*2 bf16
  size_t aggEnd  = oAggB   + al((size_t)P*D_DIM*2);
  size_t oOff    = aggEnd;
  size_t oEx     = oOff    + al((size_t)P*4);
  size_t oSorted = oEx     + al((size_t)E*4);
  size_t oW1b    = oSorted + al((size_t)E*4);
  size_t oWpb    = oW1b    + al((size_t)H_DIM*D_DIM*2);
  size_t oAb     = oWpb    + al((size_t)O_DIM*D_DIM*2);
  size_t need    = oAb     + al((size_t)L*D_DIM*2);
  (void)need; // ~230 MB; harness ws is ~1.6 GB

  float*    scores = (float*)(ws + oScores);
  unsigned* smax_o = (unsigned*)(ws + oSmax);
  float*    esum   = (float*)(ws + oEsum);
  int*      hist   = (int*)(ws + oHist);
  int*      cursor = (int*)(ws + oCursor);
  unsigned* aggb   = (unsigned*)(ws + oAggB);
  int*      offs   = (int*)(ws + oOff);
  float*    ex     = (float*)(ws + oEx);
  int*      sorted = (int*)(ws + oSorted);
  short*    W1b    = (short*)(ws + oW1b);
  short*    Wpb    = (short*)(ws + oWpb);
  short*    Ab     = (short*)(ws + oAb);

  hipMemsetAsync(d_ws, 0, smallEnd, stream);
  hipMemsetAsync(ws + oAggB, 0, (size_t)P*D_DIM*2, stream);

  dim3 b256(256);
  int eb = (E + 255) / 256;

  // weight conversions (tiny, BW-bound)
  cvt_bf16<<<128, b256, 0, stream>>>(W1, (unsigned short*)W1b, H_DIM*D_DIM/8);
  cvt_bf16<<<192, b256, 0, stream>>>(Wp, (unsigned short*)Wpb, O_DIM*D_DIM/8);

  // GEMM1: BK=32 high-occupancy (spill-fixed); emits bf16 Ab
  int nRow = (L + 127) / 128;
  int nwg  = 4 * nRow;
  gemm1_hc<<<nwg, b256, 0, stream>>>(lesion_x, W1b, b1, W2, scores, Ab, L, nwg);

  edge_pass1<<<eb, b256, 0, stream>>>(edge, E, scores, smax_o, hist);
  scan_kernel<<<1, 1024, 0, stream>>>(hist, offs, P);
  edge_pass2<<<eb, b256, 0, stream>>>(edge, E, scores, smax_o, ex, esum,
                                      offs, cursor, sorted);
  agg_kernel<<<P/4, b256, 0, stream>>>(edge, E, Ab, ex, esum, offs,
                                       hist, sorted, aggb);
  // GEMM2 + bias + LayerNorm fused (full 768-col rows per block)
  gemm2_ln<<<P/64, dim3(512), 0, stream>>>((const short*)aggb, Wpb, bp,
                                           gamma, beta, (float*)d_out);
}